// Round 1
// baseline (1573.169 us; speedup 1.0000x reference)
//
#include <hip/hip_runtime.h>

#define D_MODEL 1024
#define N_HEADS 16
#define D_K     64
#define BATCH   4
#define SEQ     2048
#define MROWS   (BATCH * SEQ)          // 8192
#define NEGF    (-1e9f)

typedef __bf16 bf16x8 __attribute__((ext_vector_type(8)));
typedef float  f32x4  __attribute__((ext_vector_type(4)));
typedef unsigned short ushort8 __attribute__((ext_vector_type(8)));
typedef unsigned short ushort4v __attribute__((ext_vector_type(4)));

__device__ inline unsigned short f2bf(float f) {
    union { float f; unsigned int u; } v; v.f = f;
    unsigned int u = v.u;
    unsigned int r = (u + 0x7fffu + ((u >> 16) & 1u)) >> 16;
    return (unsigned short)r;
}

// ---------------- prep: weights fp32 [K][N] -> bf16 [N][K] ----------------
__global__ __launch_bounds__(256) void wprep(const float* __restrict__ Wq,
                                             const float* __restrict__ Wk,
                                             const float* __restrict__ Wv,
                                             const float* __restrict__ Wo,
                                             unsigned short* __restrict__ wt) {
    __shared__ __align__(16) unsigned short t[64][65];
    int w  = blockIdx.z;
    const float* W = (w == 0) ? Wq : (w == 1) ? Wk : (w == 2) ? Wv : Wo;
    int k0 = blockIdx.x * 64, n0 = blockIdx.y * 64;
    int tid = threadIdx.x;
    int nl = tid & 63, kq = tid >> 6;
#pragma unroll
    for (int i = 0; i < 16; i++) {
        int kl = kq * 16 + i;
        t[kl][nl] = f2bf(W[(size_t)(k0 + kl) * D_MODEL + n0 + nl]);
    }
    __syncthreads();
    unsigned short* out = wt + (size_t)w * D_MODEL * D_MODEL;
#pragma unroll
    for (int p = 0; p < 2; p++) {
        int nrow = p * 32 + (tid >> 3);
        int c8   = (tid & 7) * 8;
        ushort8 o;
#pragma unroll
        for (int j = 0; j < 8; j++) o[j] = t[c8 + j][nrow];
        *reinterpret_cast<ushort8*>(out + (size_t)(n0 + nrow) * D_MODEL + k0 + c8) = o;
    }
}

// ---------------- prep: x fp32 -> bf16 ----------------
__global__ __launch_bounds__(256) void xprep(const float4* __restrict__ x,
                                             unsigned short* __restrict__ xb) {
    int i = blockIdx.x * 256 + threadIdx.x;   // over MROWS*D_MODEL/4
    float4 v = x[i];
    ushort4v o;
    o[0] = f2bf(v.x); o[1] = f2bf(v.y); o[2] = f2bf(v.z); o[3] = f2bf(v.w);
    *reinterpret_cast<ushort4v*>(xb + (size_t)i * 4) = o;
}

// ---------------- prep: mask int32 -> bitmask (bit=1 means masked) --------
__global__ __launch_bounds__(256) void mprep(const int* __restrict__ mask,
                                             unsigned long long* __restrict__ mb) {
    int row = blockIdx.x;                 // b*SEQ + q
    int tid = threadIdx.x;
    int wv  = tid >> 6;
#pragma unroll
    for (int w = 0; w < 8; w++) {
        int col = w * 256 + tid;
        int mval = mask[(size_t)row * SEQ + col];
        unsigned long long bits = __ballot(mval != 0);
        if ((tid & 63) == 0) mb[(size_t)row * 32 + w * 4 + wv] = bits;
    }
}

// ---------------- QKV projection: one 16x16 tile per wave -----------------
__global__ __launch_bounds__(64) void qkv_gemm(const unsigned short* __restrict__ xb,
                                               const unsigned short* __restrict__ wt,
                                               const float* __restrict__ bq,
                                               const float* __restrict__ bk,
                                               const float* __restrict__ bvv,
                                               unsigned short* __restrict__ qb,
                                               unsigned short* __restrict__ kb,
                                               unsigned short* __restrict__ vt) {
    int wsel = blockIdx.z;
    int n0 = blockIdx.x * 16, m0 = blockIdx.y * 16;
    int lane = threadIdx.x;
    int c = lane & 15, g = lane >> 4;
    const unsigned short* A  = xb + (size_t)(m0 + c) * D_MODEL + g * 8;
    const unsigned short* Bt = wt + (size_t)wsel * D_MODEL * D_MODEL + (size_t)(n0 + c) * D_MODEL + g * 8;
    f32x4 acc = {0.f, 0.f, 0.f, 0.f};
    for (int k = 0; k < D_MODEL; k += 32) {
        bf16x8 a = *reinterpret_cast<const bf16x8*>(A + k);
        bf16x8 b = *reinterpret_cast<const bf16x8*>(Bt + k);
        acc = __builtin_amdgcn_mfma_f32_16x16x32_bf16(a, b, acc, 0, 0, 0);
    }
    const float* bias = (wsel == 0) ? bq : (wsel == 1) ? bk : bvv;
    float bb = bias[n0 + c];
    int bidx = m0 >> 11, s0 = m0 & (SEQ - 1);
    int h = n0 >> 6, dk0 = n0 & 63;
    if (wsel < 2) {
        unsigned short* outp = (wsel == 0) ? qb : kb;
#pragma unroll
        for (int r = 0; r < 4; r++) {
            int row = g * 4 + r;
            outp[(((size_t)(bidx * N_HEADS + h) * SEQ + s0 + row) << 6) + dk0 + c] = f2bf(acc[r] + bb);
        }
    } else {
        __shared__ __align__(16) unsigned short tl[16][24];
#pragma unroll
        for (int r = 0; r < 4; r++) tl[g * 4 + r][c] = f2bf(acc[r] + bb);
        __syncthreads();
        if (lane < 32) {
            int dkl = lane >> 1, sl = (lane & 1) * 8;
            ushort8 o;
#pragma unroll
            for (int j = 0; j < 8; j++) o[j] = tl[sl + j][dkl];
            *reinterpret_cast<ushort8*>(vt + ((size_t)(bidx * N_HEADS + h) * 64 + dk0 + dkl) * SEQ + s0 + sl) = o;
        }
    }
}

// ---------------- flash attention: 16-query tile per wave -----------------
__global__ __launch_bounds__(256) void attn(const unsigned short* __restrict__ qb,
                                            const unsigned short* __restrict__ kb,
                                            const unsigned short* __restrict__ vt,
                                            const unsigned long long* __restrict__ mb,
                                            unsigned short* __restrict__ ctx) {
    __shared__ __align__(16) unsigned short lp[4][16][32];
    int tid = threadIdx.x;
    int wv = tid >> 6, lane = tid & 63;
    int c = lane & 15, g = lane >> 4;
    int t_id = blockIdx.x * 4 + wv;
    int b = t_id >> 11;
    int h = (t_id >> 7) & 15;
    int q0 = (t_id & 127) << 4;
    int bh = b * N_HEADS + h;
    const unsigned short* qbase = qb + (size_t)bh * SEQ * 64;
    const unsigned short* kbase = kb + (size_t)bh * SEQ * 64;
    const unsigned short* vbase = vt + (size_t)bh * 64 * SEQ;

    bf16x8 qf[2];
    qf[0] = *reinterpret_cast<const bf16x8*>(qbase + (size_t)(q0 + c) * 64 + g * 8);
    qf[1] = *reinterpret_cast<const bf16x8*>(qbase + (size_t)(q0 + c) * 64 + 32 + g * 8);

    float m_[4], l_[4];
    f32x4 po[4];
#pragma unroll
    for (int r = 0; r < 4; r++) { m_[r] = -INFINITY; l_[r] = 0.f; }
#pragma unroll
    for (int t = 0; t < 4; t++) po[t] = f32x4{0.f, 0.f, 0.f, 0.f};

    for (int key0 = 0; key0 < SEQ; key0 += 32) {
        f32x4 s[2] = {{0.f,0.f,0.f,0.f},{0.f,0.f,0.f,0.f}};
#pragma unroll
        for (int st = 0; st < 2; st++) {
            const unsigned short* kp = kbase + (size_t)(key0 + st * 16 + c) * 64 + g * 8;
            s[st] = __builtin_amdgcn_mfma_f32_16x16x32_bf16(qf[0], *reinterpret_cast<const bf16x8*>(kp), s[st], 0, 0, 0);
            s[st] = __builtin_amdgcn_mfma_f32_16x16x32_bf16(qf[1], *reinterpret_cast<const bf16x8*>(kp + 32), s[st], 0, 0, 0);
        }
        float al[4];
#pragma unroll
        for (int r = 0; r < 4; r++) {
            int qrow = q0 + g * 4 + r;
            unsigned long long w = mb[((size_t)b * SEQ + qrow) * 32 + (key0 >> 6)];
            int base = key0 & 32;
            float s0 = ((w >> (base + c)) & 1ull) ? NEGF : s[0][r] * 0.125f;
            float s1 = ((w >> (base + 16 + c)) & 1ull) ? NEGF : s[1][r] * 0.125f;
            float tm = fmaxf(s0, s1);
            tm = fmaxf(tm, __shfl_xor(tm, 1));
            tm = fmaxf(tm, __shfl_xor(tm, 2));
            tm = fmaxf(tm, __shfl_xor(tm, 4));
            tm = fmaxf(tm, __shfl_xor(tm, 8));
            float mn = fmaxf(m_[r], tm);
            float a  = __expf(m_[r] - mn);
            float p0 = __expf(s0 - mn);
            float p1 = __expf(s1 - mn);
            float rs = p0 + p1;
            rs += __shfl_xor(rs, 1);
            rs += __shfl_xor(rs, 2);
            rs += __shfl_xor(rs, 4);
            rs += __shfl_xor(rs, 8);
            l_[r] = l_[r] * a + rs;
            m_[r] = mn;
            al[r] = a;
            lp[wv][g * 4 + r][c]      = f2bf(p0);
            lp[wv][g * 4 + r][16 + c] = f2bf(p1);
        }
#pragma unroll
        for (int t = 0; t < 4; t++)
#pragma unroll
            for (int r = 0; r < 4; r++) po[t][r] *= al[r];
        __syncthreads();
        bf16x8 pf = *reinterpret_cast<const bf16x8*>(&lp[wv][c][g * 8]);
#pragma unroll
        for (int t = 0; t < 4; t++) {
            bf16x8 vf = *reinterpret_cast<const bf16x8*>(vbase + (size_t)(t * 16 + c) * SEQ + key0 + g * 8);
            po[t] = __builtin_amdgcn_mfma_f32_16x16x32_bf16(pf, vf, po[t], 0, 0, 0);
        }
        __syncthreads();
    }
    float inv[4];
#pragma unroll
    for (int r = 0; r < 4; r++) inv[r] = 1.f / l_[r];
#pragma unroll
    for (int t = 0; t < 4; t++)
#pragma unroll
        for (int r = 0; r < 4; r++) {
            int row = g * 4 + r;
            ctx[((size_t)b * SEQ + q0 + row) * D_MODEL + h * 64 + t * 16 + c] = f2bf(po[t][r] * inv[r]);
        }
}

// ---------------- output projection -> fp32 ----------------
__global__ __launch_bounds__(64) void oproj(const unsigned short* __restrict__ ctx,
                                            const unsigned short* __restrict__ wt,
                                            const float* __restrict__ bo,
                                            float* __restrict__ out) {
    int n0 = blockIdx.x * 16, m0 = blockIdx.y * 16;
    int lane = threadIdx.x;
    int c = lane & 15, g = lane >> 4;
    const unsigned short* A  = ctx + (size_t)(m0 + c) * D_MODEL + g * 8;
    const unsigned short* Bt = wt + (size_t)3 * D_MODEL * D_MODEL + (size_t)(n0 + c) * D_MODEL + g * 8;
    f32x4 acc = {0.f, 0.f, 0.f, 0.f};
    for (int k = 0; k < D_MODEL; k += 32) {
        bf16x8 a = *reinterpret_cast<const bf16x8*>(A + k);
        bf16x8 b = *reinterpret_cast<const bf16x8*>(Bt + k);
        acc = __builtin_amdgcn_mfma_f32_16x16x32_bf16(a, b, acc, 0, 0, 0);
    }
    float bb = bo[n0 + c];
#pragma unroll
    for (int r = 0; r < 4; r++) {
        int row = g * 4 + r;
        out[(size_t)(m0 + row) * D_MODEL + n0 + c] = acc[r] + bb;
    }
}

extern "C" void kernel_launch(void* const* d_in, const int* in_sizes, int n_in,
                              void* d_out, int out_size, void* d_ws, size_t ws_size,
                              hipStream_t stream) {
    const float* x    = (const float*)d_in[0];
    const int*   mask = (const int*)d_in[1];
    const float* Wq = (const float*)d_in[2];
    const float* bq = (const float*)d_in[3];
    const float* Wk = (const float*)d_in[4];
    const float* bk = (const float*)d_in[5];
    const float* Wv = (const float*)d_in[6];
    const float* bv = (const float*)d_in[7];
    const float* Wo = (const float*)d_in[8];
    const float* bo = (const float*)d_in[9];
    float* out = (float*)d_out;

    char* ws = (char*)d_ws;
    const size_t MB = 1024 * 1024;
    unsigned short* wt  = (unsigned short*)(ws + 0 * MB);    // 4x 1024x1024 bf16 = 8 MB
    unsigned short* xb  = (unsigned short*)(ws + 8 * MB);    // 8192x1024 bf16   = 16 MB
    unsigned short* qb  = (unsigned short*)(ws + 24 * MB);   // [B,H,S,dk] bf16  = 16 MB
    unsigned short* kb  = (unsigned short*)(ws + 40 * MB);   // [B,H,S,dk] bf16  = 16 MB
    unsigned short* vt  = (unsigned short*)(ws + 56 * MB);   // [B,H,dk,S] bf16  = 16 MB
    unsigned short* ctx = (unsigned short*)(ws + 72 * MB);   // [B,S,D] bf16     = 16 MB
    unsigned long long* mb = (unsigned long long*)(ws + 88 * MB); // 8192x32 u64 = 2 MB

    wprep<<<dim3(16, 16, 4), 256, 0, stream>>>(Wq, Wk, Wv, Wo, wt);
    xprep<<<dim3(MROWS * D_MODEL / 4 / 256), 256, 0, stream>>>((const float4*)x, xb);
    mprep<<<dim3(MROWS), 256, 0, stream>>>(mask, mb);
    qkv_gemm<<<dim3(64, 512, 3), 64, 0, stream>>>(xb, wt, bq, bk, bv, qb, kb, vt);
    attn<<<dim3(2048), 256, 0, stream>>>(qb, kb, vt, mb, ctx);
    oproj<<<dim3(64, 512), 64, 0, stream>>>(ctx, wt, bo, out);
}

// Round 2
// 780.100 us; speedup vs baseline: 2.0166x; 2.0166x over previous
//
#include <hip/hip_runtime.h>

#define D_MODEL 1024
#define N_HEADS 16
#define D_K     64
#define BATCH   4
#define SEQ     2048
#define MROWS   (BATCH * SEQ)          // 8192
#define NEGF    (-1e9f)

typedef __bf16 bf16x8 __attribute__((ext_vector_type(8)));
typedef float  f32x4  __attribute__((ext_vector_type(4)));
typedef unsigned short ushort8 __attribute__((ext_vector_type(8)));
typedef unsigned short ushort4v __attribute__((ext_vector_type(4)));

__device__ inline unsigned short f2bf(float f) {
    union { float f; unsigned int u; } v; v.f = f;
    unsigned int u = v.u;
    unsigned int r = (u + 0x7fffu + ((u >> 16) & 1u)) >> 16;
    return (unsigned short)r;
}

__device__ inline void load_lds16(const void* g, void* l) {
    __builtin_amdgcn_global_load_lds(
        (const __attribute__((address_space(1))) unsigned int*)g,
        (__attribute__((address_space(3))) unsigned int*)l, 16, 0, 0);
}

// ---------------- prep: weights fp32 [K][N] -> bf16 [N][K] ----------------
__global__ __launch_bounds__(256) void wprep(const float* __restrict__ Wq,
                                             const float* __restrict__ Wk,
                                             const float* __restrict__ Wv,
                                             const float* __restrict__ Wo,
                                             unsigned short* __restrict__ wt) {
    __shared__ __align__(16) unsigned short t[64][65];
    int w  = blockIdx.z;
    const float* W = (w == 0) ? Wq : (w == 1) ? Wk : (w == 2) ? Wv : Wo;
    int k0 = blockIdx.x * 64, n0 = blockIdx.y * 64;
    int tid = threadIdx.x;
    int nl = tid & 63, kq = tid >> 6;
#pragma unroll
    for (int i = 0; i < 16; i++) {
        int kl = kq * 16 + i;
        t[kl][nl] = f2bf(W[(size_t)(k0 + kl) * D_MODEL + n0 + nl]);
    }
    __syncthreads();
    unsigned short* out = wt + (size_t)w * D_MODEL * D_MODEL;
#pragma unroll
    for (int p = 0; p < 2; p++) {
        int nrow = p * 32 + (tid >> 3);
        int c8   = (tid & 7) * 8;
        ushort8 o;
#pragma unroll
        for (int j = 0; j < 8; j++) o[j] = t[c8 + j][nrow];
        *reinterpret_cast<ushort8*>(out + (size_t)(n0 + nrow) * D_MODEL + k0 + c8) = o;
    }
}

// ---------------- prep: x fp32 -> bf16 ----------------
__global__ __launch_bounds__(256) void xprep(const float4* __restrict__ x,
                                             unsigned short* __restrict__ xb) {
    int i = blockIdx.x * 256 + threadIdx.x;   // over MROWS*D_MODEL/4
    float4 v = x[i];
    ushort4v o;
    o[0] = f2bf(v.x); o[1] = f2bf(v.y); o[2] = f2bf(v.z); o[3] = f2bf(v.w);
    *reinterpret_cast<ushort4v*>(xb + (size_t)i * 4) = o;
}

// ---------------- prep: mask int32 -> bitmask (bit=1 means masked) --------
__global__ __launch_bounds__(256) void mprep(const int* __restrict__ mask,
                                             unsigned long long* __restrict__ mb) {
    int row = blockIdx.x;                 // b*SEQ + q
    int tid = threadIdx.x;
    int wv  = tid >> 6;
#pragma unroll
    for (int w = 0; w < 8; w++) {
        int col = w * 256 + tid;
        int mval = mask[(size_t)row * SEQ + col];
        unsigned long long bits = __ballot(mval != 0);
        if ((tid & 63) == 0) mb[(size_t)row * 32 + w * 4 + wv] = bits;
    }
}

// ============ fused QKV GEMM: m97 structure, M=8192 N=3072 K=1024 =========
// 128x128 tile, BK=32, 256 thr = 4 waves (2x2 of 64x64), global_load_lds w=16
__global__ __launch_bounds__(256) void qkv_gemm(const unsigned short* __restrict__ xb,
                                                const unsigned short* __restrict__ wt,
                                                const float* __restrict__ bq,
                                                const float* __restrict__ bk,
                                                const float* __restrict__ bvv,
                                                unsigned short* __restrict__ qb,
                                                unsigned short* __restrict__ kb,
                                                unsigned short* __restrict__ vt) {
    __shared__ __align__(16) unsigned short lds_a[128 * 32];
    __shared__ __align__(16) unsigned short lds_b[128 * 32];
    int tid = threadIdx.x;
    int wave = tid >> 6, lane = tid & 63;
    int c = lane & 15, g = lane >> 4;
    int wave_m = (wave & 1) * 64, wave_n = (wave >> 1) * 64;
    int nblk = blockIdx.x * 128, mblk = blockIdx.y * 128;

    // staging addresses (row/group constant; only k0 advances)
    int oct0 = wave * 128 + lane, oct1 = oct0 + 64;
    int ra0 = oct0 >> 2, ga0 = ((oct0 & 3) ^ (ra0 & 3)) * 8;
    int ra1 = oct1 >> 2, ga1 = ((oct1 & 3) ^ (ra1 & 3)) * 8;
    const unsigned short* pa0 = xb + (size_t)(mblk + ra0) * D_MODEL + ga0;
    const unsigned short* pa1 = xb + (size_t)(mblk + ra1) * D_MODEL + ga1;
    const unsigned short* pb0 = wt + (size_t)(nblk + ra0) * D_MODEL + ga0;
    const unsigned short* pb1 = wt + (size_t)(nblk + ra1) * D_MODEL + ga1;
    unsigned short* la0 = lds_a + wave * 1024;
    unsigned short* la1 = la0 + 512;
    unsigned short* lb0 = lds_b + wave * 1024;
    unsigned short* lb1 = lb0 + 512;

    // fragment LDS byte offsets (constant across K)
    int aoff[4], boff[4];
#pragma unroll
    for (int mi = 0; mi < 4; mi++) {
        int row = wave_m + mi * 16 + c;
        aoff[mi] = (row * 4 + (g ^ (row & 3))) * 16;
    }
#pragma unroll
    for (int ni = 0; ni < 4; ni++) {
        int row = wave_n + ni * 16 + c;
        boff[ni] = (row * 4 + (g ^ (row & 3))) * 16;
    }

    f32x4 acc[4][4];
#pragma unroll
    for (int mi = 0; mi < 4; mi++)
#pragma unroll
        for (int ni = 0; ni < 4; ni++) acc[mi][ni] = f32x4{0.f, 0.f, 0.f, 0.f};

    for (int k0 = 0; k0 < D_MODEL; k0 += 32) {
        load_lds16(pa0 + k0, la0);
        load_lds16(pa1 + k0, la1);
        load_lds16(pb0 + k0, lb0);
        load_lds16(pb1 + k0, lb1);
        __syncthreads();
        bf16x8 af[4], bfr[4];
#pragma unroll
        for (int mi = 0; mi < 4; mi++)
            af[mi] = *reinterpret_cast<const bf16x8*>(reinterpret_cast<const char*>(lds_a) + aoff[mi]);
#pragma unroll
        for (int ni = 0; ni < 4; ni++)
            bfr[ni] = *reinterpret_cast<const bf16x8*>(reinterpret_cast<const char*>(lds_b) + boff[ni]);
#pragma unroll
        for (int mi = 0; mi < 4; mi++)
#pragma unroll
            for (int ni = 0; ni < 4; ni++)
                acc[mi][ni] = __builtin_amdgcn_mfma_f32_16x16x32_bf16(af[mi], bfr[ni], acc[mi][ni], 0, 0, 0);
        __syncthreads();
    }

    // epilogue: wave-uniform routing (128 | 1024 so wsel,h uniform per wave)
    int nb = nblk + wave_n;
    int wsel = nb >> 10;
    int h = (nb >> 6) & 15;
    int dk0 = nb & 63;
    int mglob = mblk + wave_m;
    int b = mglob >> 11;
    int s0 = mglob & (SEQ - 1);
    size_t bh = (size_t)(b * N_HEADS + h);
    const float* bias = (wsel == 0) ? bq : (wsel == 1) ? bk : bvv;
    int nn = nb & (D_MODEL - 1);
    float bval[4];
#pragma unroll
    for (int ni = 0; ni < 4; ni++) bval[ni] = bias[nn + ni * 16 + c];

    if (wsel < 2) {
        unsigned short* outp = wsel ? kb : qb;
#pragma unroll
        for (int mi = 0; mi < 4; mi++)
#pragma unroll
            for (int ni = 0; ni < 4; ni++) {
                int dk = dk0 + ni * 16 + c;
#pragma unroll
                for (int r = 0; r < 4; r++) {
                    int s = s0 + mi * 16 + g * 4 + r;
                    outp[(bh * SEQ + s) * 64 + dk] = f2bf(acc[mi][ni][r] + bval[ni]);
                }
            }
    } else {
#pragma unroll
        for (int mi = 0; mi < 4; mi++)
#pragma unroll
            for (int ni = 0; ni < 4; ni++) {
                int dk = dk0 + ni * 16 + c;
                int s = s0 + mi * 16 + g * 4;
                ushort4v o;
#pragma unroll
                for (int r = 0; r < 4; r++) o[r] = f2bf(acc[mi][ni][r] + bval[ni]);
                *reinterpret_cast<ushort4v*>(vt + (bh * 64 + dk) * SEQ + s) = o;
            }
    }
}

// ---------------- flash attention: 16-query tile per wave -----------------
__global__ __launch_bounds__(256) void attn(const unsigned short* __restrict__ qb,
                                            const unsigned short* __restrict__ kb,
                                            const unsigned short* __restrict__ vt,
                                            const unsigned long long* __restrict__ mb,
                                            unsigned short* __restrict__ ctx) {
    __shared__ __align__(16) unsigned short lp[4][16][32];
    int tid = threadIdx.x;
    int wv = tid >> 6, lane = tid & 63;
    int c = lane & 15, g = lane >> 4;
    int t_id = blockIdx.x * 4 + wv;
    int b = t_id >> 11;
    int h = (t_id >> 7) & 15;
    int q0 = (t_id & 127) << 4;
    int bh = b * N_HEADS + h;
    const unsigned short* qbase = qb + (size_t)bh * SEQ * 64;
    const unsigned short* kbase = kb + (size_t)bh * SEQ * 64;
    const unsigned short* vbase = vt + (size_t)bh * 64 * SEQ;

    bf16x8 qf[2];
    qf[0] = *reinterpret_cast<const bf16x8*>(qbase + (size_t)(q0 + c) * 64 + g * 8);
    qf[1] = *reinterpret_cast<const bf16x8*>(qbase + (size_t)(q0 + c) * 64 + 32 + g * 8);

    float m_[4], l_[4];
    f32x4 po[4];
#pragma unroll
    for (int r = 0; r < 4; r++) { m_[r] = -INFINITY; l_[r] = 0.f; }
#pragma unroll
    for (int t = 0; t < 4; t++) po[t] = f32x4{0.f, 0.f, 0.f, 0.f};

    for (int key0 = 0; key0 < SEQ; key0 += 32) {
        f32x4 s[2] = {{0.f,0.f,0.f,0.f},{0.f,0.f,0.f,0.f}};
#pragma unroll
        for (int st = 0; st < 2; st++) {
            const unsigned short* kp = kbase + (size_t)(key0 + st * 16 + c) * 64 + g * 8;
            s[st] = __builtin_amdgcn_mfma_f32_16x16x32_bf16(qf[0], *reinterpret_cast<const bf16x8*>(kp), s[st], 0, 0, 0);
            s[st] = __builtin_amdgcn_mfma_f32_16x16x32_bf16(qf[1], *reinterpret_cast<const bf16x8*>(kp + 32), s[st], 0, 0, 0);
        }
        float al[4];
#pragma unroll
        for (int r = 0; r < 4; r++) {
            int qrow = q0 + g * 4 + r;
            unsigned long long w = mb[((size_t)b * SEQ + qrow) * 32 + (key0 >> 6)];
            int base = key0 & 32;
            float s0 = ((w >> (base + c)) & 1ull) ? NEGF : s[0][r] * 0.125f;
            float s1 = ((w >> (base + 16 + c)) & 1ull) ? NEGF : s[1][r] * 0.125f;
            float tm = fmaxf(s0, s1);
            tm = fmaxf(tm, __shfl_xor(tm, 1));
            tm = fmaxf(tm, __shfl_xor(tm, 2));
            tm = fmaxf(tm, __shfl_xor(tm, 4));
            tm = fmaxf(tm, __shfl_xor(tm, 8));
            float mn = fmaxf(m_[r], tm);
            float a  = __expf(m_[r] - mn);
            float p0 = __expf(s0 - mn);
            float p1 = __expf(s1 - mn);
            float rs = p0 + p1;
            rs += __shfl_xor(rs, 1);
            rs += __shfl_xor(rs, 2);
            rs += __shfl_xor(rs, 4);
            rs += __shfl_xor(rs, 8);
            l_[r] = l_[r] * a + rs;
            m_[r] = mn;
            al[r] = a;
            lp[wv][g * 4 + r][c]      = f2bf(p0);
            lp[wv][g * 4 + r][16 + c] = f2bf(p1);
        }
#pragma unroll
        for (int t = 0; t < 4; t++)
#pragma unroll
            for (int r = 0; r < 4; r++) po[t][r] *= al[r];
        __syncthreads();
        bf16x8 pf = *reinterpret_cast<const bf16x8*>(&lp[wv][c][g * 8]);
#pragma unroll
        for (int t = 0; t < 4; t++) {
            bf16x8 vf = *reinterpret_cast<const bf16x8*>(vbase + (size_t)(t * 16 + c) * SEQ + key0 + g * 8);
            po[t] = __builtin_amdgcn_mfma_f32_16x16x32_bf16(pf, vf, po[t], 0, 0, 0);
        }
        __syncthreads();
    }
    float inv[4];
#pragma unroll
    for (int r = 0; r < 4; r++) inv[r] = 1.f / l_[r];
#pragma unroll
    for (int t = 0; t < 4; t++)
#pragma unroll
        for (int r = 0; r < 4; r++) {
            int row = g * 4 + r;
            ctx[((size_t)b * SEQ + q0 + row) * D_MODEL + h * 64 + t * 16 + c] = f2bf(po[t][r] * inv[r]);
        }
}

// ============ output projection: m97 structure, M=8192 N=1024 K=1024 ======
__global__ __launch_bounds__(256) void oproj(const unsigned short* __restrict__ ctx,
                                             const unsigned short* __restrict__ wt,
                                             const float* __restrict__ bo,
                                             float* __restrict__ out) {
    __shared__ __align__(16) unsigned short lds_a[128 * 32];
    __shared__ __align__(16) unsigned short lds_b[128 * 32];
    int tid = threadIdx.x;
    int wave = tid >> 6, lane = tid & 63;
    int c = lane & 15, g = lane >> 4;
    int wave_m = (wave & 1) * 64, wave_n = (wave >> 1) * 64;
    int nblk = blockIdx.x * 128, mblk = blockIdx.y * 128;
    const unsigned short* wo = wt + (size_t)3 * D_MODEL * D_MODEL;

    int oct0 = wave * 128 + lane, oct1 = oct0 + 64;
    int ra0 = oct0 >> 2, ga0 = ((oct0 & 3) ^ (ra0 & 3)) * 8;
    int ra1 = oct1 >> 2, ga1 = ((oct1 & 3) ^ (ra1 & 3)) * 8;
    const unsigned short* pa0 = ctx + (size_t)(mblk + ra0) * D_MODEL + ga0;
    const unsigned short* pa1 = ctx + (size_t)(mblk + ra1) * D_MODEL + ga1;
    const unsigned short* pb0 = wo + (size_t)(nblk + ra0) * D_MODEL + ga0;
    const unsigned short* pb1 = wo + (size_t)(nblk + ra1) * D_MODEL + ga1;
    unsigned short* la0 = lds_a + wave * 1024;
    unsigned short* la1 = la0 + 512;
    unsigned short* lb0 = lds_b + wave * 1024;
    unsigned short* lb1 = lb0 + 512;

    int aoff[4], boff[4];
#pragma unroll
    for (int mi = 0; mi < 4; mi++) {
        int row = wave_m + mi * 16 + c;
        aoff[mi] = (row * 4 + (g ^ (row & 3))) * 16;
    }
#pragma unroll
    for (int ni = 0; ni < 4; ni++) {
        int row = wave_n + ni * 16 + c;
        boff[ni] = (row * 4 + (g ^ (row & 3))) * 16;
    }

    f32x4 acc[4][4];
#pragma unroll
    for (int mi = 0; mi < 4; mi++)
#pragma unroll
        for (int ni = 0; ni < 4; ni++) acc[mi][ni] = f32x4{0.f, 0.f, 0.f, 0.f};

    for (int k0 = 0; k0 < D_MODEL; k0 += 32) {
        load_lds16(pa0 + k0, la0);
        load_lds16(pa1 + k0, la1);
        load_lds16(pb0 + k0, lb0);
        load_lds16(pb1 + k0, lb1);
        __syncthreads();
        bf16x8 af[4], bfr[4];
#pragma unroll
        for (int mi = 0; mi < 4; mi++)
            af[mi] = *reinterpret_cast<const bf16x8*>(reinterpret_cast<const char*>(lds_a) + aoff[mi]);
#pragma unroll
        for (int ni = 0; ni < 4; ni++)
            bfr[ni] = *reinterpret_cast<const bf16x8*>(reinterpret_cast<const char*>(lds_b) + boff[ni]);
#pragma unroll
        for (int mi = 0; mi < 4; mi++)
#pragma unroll
            for (int ni = 0; ni < 4; ni++)
                acc[mi][ni] = __builtin_amdgcn_mfma_f32_16x16x32_bf16(af[mi], bfr[ni], acc[mi][ni], 0, 0, 0);
        __syncthreads();
    }

    float bval[4];
#pragma unroll
    for (int ni = 0; ni < 4; ni++) bval[ni] = bo[nblk + wave_n + ni * 16 + c];
#pragma unroll
    for (int mi = 0; mi < 4; mi++)
#pragma unroll
        for (int ni = 0; ni < 4; ni++) {
            int n = nblk + wave_n + ni * 16 + c;
#pragma unroll
            for (int r = 0; r < 4; r++) {
                int m = mblk + wave_m + mi * 16 + g * 4 + r;
                out[(size_t)m * D_MODEL + n] = acc[mi][ni][r] + bval[ni];
            }
        }
}

extern "C" void kernel_launch(void* const* d_in, const int* in_sizes, int n_in,
                              void* d_out, int out_size, void* d_ws, size_t ws_size,
                              hipStream_t stream) {
    const float* x    = (const float*)d_in[0];
    const int*   mask = (const int*)d_in[1];
    const float* Wq = (const float*)d_in[2];
    const float* bq = (const float*)d_in[3];
    const float* Wk = (const float*)d_in[4];
    const float* bk = (const float*)d_in[5];
    const float* Wv = (const float*)d_in[6];
    const float* bv = (const float*)d_in[7];
    const float* Wo = (const float*)d_in[8];
    const float* bo = (const float*)d_in[9];
    float* out = (float*)d_out;

    char* ws = (char*)d_ws;
    const size_t MB = 1024 * 1024;
    unsigned short* wt  = (unsigned short*)(ws + 0 * MB);    // 4x 1024x1024 bf16 = 8 MB
    unsigned short* xb  = (unsigned short*)(ws + 8 * MB);    // 8192x1024 bf16   = 16 MB
    unsigned short* qb  = (unsigned short*)(ws + 24 * MB);   // [B,H,S,dk] bf16  = 16 MB
    unsigned short* kb  = (unsigned short*)(ws + 40 * MB);   // [B,H,S,dk] bf16  = 16 MB
    unsigned short* vt  = (unsigned short*)(ws + 56 * MB);   // [B,H,dk,S] bf16  = 16 MB
    unsigned short* ctx = (unsigned short*)(ws + 72 * MB);   // [B,S,D] bf16     = 16 MB
    unsigned long long* mb = (unsigned long long*)(ws + 88 * MB); // 8192x32 u64 = 2 MB

    wprep<<<dim3(16, 16, 4), 256, 0, stream>>>(Wq, Wk, Wv, Wo, wt);
    xprep<<<dim3(MROWS * D_MODEL / 4 / 256), 256, 0, stream>>>((const float4*)x, xb);
    mprep<<<dim3(MROWS), 256, 0, stream>>>(mask, mb);
    qkv_gemm<<<dim3(24, 64), 256, 0, stream>>>(xb, wt, bq, bk, bv, qb, kb, vt);
    attn<<<dim3(2048), 256, 0, stream>>>(qb, kb, vt, mb, ctx);
    oproj<<<dim3(8, 64), 256, 0, stream>>>(ctx, wt, bo, out);
}

// Round 3
// 408.773 us; speedup vs baseline: 3.8485x; 1.9084x over previous
//
#include <hip/hip_runtime.h>

#define D_MODEL 1024
#define N_HEADS 16
#define D_K     64
#define BATCH   4
#define SEQ     2048
#define MROWS   (BATCH * SEQ)          // 8192

typedef __bf16 bf16x8 __attribute__((ext_vector_type(8)));
typedef float  f32x4  __attribute__((ext_vector_type(4)));
typedef unsigned short ushort8 __attribute__((ext_vector_type(8)));
typedef unsigned short ushort4v __attribute__((ext_vector_type(4)));

__device__ inline unsigned short f2bf(float f) {
    union { float f; unsigned int u; } v; v.f = f;
    unsigned int u = v.u;
    unsigned int r = (u + 0x7fffu + ((u >> 16) & 1u)) >> 16;
    return (unsigned short)r;
}

__device__ inline void load_lds16(const void* g, void* l) {
    __builtin_amdgcn_global_load_lds(
        (const __attribute__((address_space(1))) unsigned int*)g,
        (__attribute__((address_space(3))) unsigned int*)l, 16, 0, 0);
}

// ---------------- prep: weights fp32 [K][N] -> bf16 [N][K] ----------------
__global__ __launch_bounds__(256) void wprep(const float* __restrict__ Wq,
                                             const float* __restrict__ Wk,
                                             const float* __restrict__ Wv,
                                             const float* __restrict__ Wo,
                                             unsigned short* __restrict__ wt) {
    __shared__ __align__(16) unsigned short t[64][65];
    int w  = blockIdx.z;
    const float* W = (w == 0) ? Wq : (w == 1) ? Wk : (w == 2) ? Wv : Wo;
    int k0 = blockIdx.x * 64, n0 = blockIdx.y * 64;
    int tid = threadIdx.x;
    int nl = tid & 63, kq = tid >> 6;
#pragma unroll
    for (int i = 0; i < 16; i++) {
        int kl = kq * 16 + i;
        t[kl][nl] = f2bf(W[(size_t)(k0 + kl) * D_MODEL + n0 + nl]);
    }
    __syncthreads();
    unsigned short* out = wt + (size_t)w * D_MODEL * D_MODEL;
#pragma unroll
    for (int p = 0; p < 2; p++) {
        int nrow = p * 32 + (tid >> 3);
        int c8   = (tid & 7) * 8;
        ushort8 o;
#pragma unroll
        for (int j = 0; j < 8; j++) o[j] = t[c8 + j][nrow];
        *reinterpret_cast<ushort8*>(out + (size_t)(n0 + nrow) * D_MODEL + k0 + c8) = o;
    }
}

// ---------------- prep: x fp32 -> bf16 ----------------
__global__ __launch_bounds__(256) void xprep(const float4* __restrict__ x,
                                             unsigned short* __restrict__ xb) {
    int i = blockIdx.x * 256 + threadIdx.x;   // over MROWS*D_MODEL/4
    float4 v = x[i];
    ushort4v o;
    o[0] = f2bf(v.x); o[1] = f2bf(v.y); o[2] = f2bf(v.z); o[3] = f2bf(v.w);
    *reinterpret_cast<ushort4v*>(xb + (size_t)i * 4) = o;
}

// ---------------- prep: mask int32 -> bitmask (bit=1 means masked) --------
__global__ __launch_bounds__(256) void mprep(const int* __restrict__ mask,
                                             unsigned long long* __restrict__ mb) {
    int row = blockIdx.x;                 // b*SEQ + q
    int tid = threadIdx.x;
    int wv  = tid >> 6;
#pragma unroll
    for (int w = 0; w < 8; w++) {
        int col = w * 256 + tid;
        int mval = mask[(size_t)row * SEQ + col];
        unsigned long long bits = __ballot(mval != 0);
        if ((tid & 63) == 0) mb[(size_t)row * 32 + w * 4 + wv] = bits;
    }
}

// ============ fused QKV GEMM: m97 structure, M=8192 N=3072 K=1024 =========
__global__ __launch_bounds__(256) void qkv_gemm(const unsigned short* __restrict__ xb,
                                                const unsigned short* __restrict__ wt,
                                                const float* __restrict__ bq,
                                                const float* __restrict__ bk,
                                                const float* __restrict__ bvv,
                                                unsigned short* __restrict__ qb,
                                                unsigned short* __restrict__ kb,
                                                unsigned short* __restrict__ vt) {
    __shared__ __align__(16) unsigned short lds_a[128 * 32];
    __shared__ __align__(16) unsigned short lds_b[128 * 32];
    int tid = threadIdx.x;
    int wave = tid >> 6, lane = tid & 63;
    int c = lane & 15, g = lane >> 4;
    int wave_m = (wave & 1) * 64, wave_n = (wave >> 1) * 64;
    int nblk = blockIdx.x * 128, mblk = blockIdx.y * 128;

    int oct0 = wave * 128 + lane, oct1 = oct0 + 64;
    int ra0 = oct0 >> 2, ga0 = ((oct0 & 3) ^ (ra0 & 3)) * 8;
    int ra1 = oct1 >> 2, ga1 = ((oct1 & 3) ^ (ra1 & 3)) * 8;
    const unsigned short* pa0 = xb + (size_t)(mblk + ra0) * D_MODEL + ga0;
    const unsigned short* pa1 = xb + (size_t)(mblk + ra1) * D_MODEL + ga1;
    const unsigned short* pb0 = wt + (size_t)(nblk + ra0) * D_MODEL + ga0;
    const unsigned short* pb1 = wt + (size_t)(nblk + ra1) * D_MODEL + ga1;
    unsigned short* la0 = lds_a + wave * 1024;
    unsigned short* la1 = la0 + 512;
    unsigned short* lb0 = lds_b + wave * 1024;
    unsigned short* lb1 = lb0 + 512;

    int aoff[4], boff[4];
#pragma unroll
    for (int mi = 0; mi < 4; mi++) {
        int row = wave_m + mi * 16 + c;
        aoff[mi] = (row * 4 + (g ^ (row & 3))) * 16;
    }
#pragma unroll
    for (int ni = 0; ni < 4; ni++) {
        int row = wave_n + ni * 16 + c;
        boff[ni] = (row * 4 + (g ^ (row & 3))) * 16;
    }

    f32x4 acc[4][4];
#pragma unroll
    for (int mi = 0; mi < 4; mi++)
#pragma unroll
        for (int ni = 0; ni < 4; ni++) acc[mi][ni] = f32x4{0.f, 0.f, 0.f, 0.f};

    for (int k0 = 0; k0 < D_MODEL; k0 += 32) {
        load_lds16(pa0 + k0, la0);
        load_lds16(pa1 + k0, la1);
        load_lds16(pb0 + k0, lb0);
        load_lds16(pb1 + k0, lb1);
        __syncthreads();
        bf16x8 af[4], bfr[4];
#pragma unroll
        for (int mi = 0; mi < 4; mi++)
            af[mi] = *reinterpret_cast<const bf16x8*>(reinterpret_cast<const char*>(lds_a) + aoff[mi]);
#pragma unroll
        for (int ni = 0; ni < 4; ni++)
            bfr[ni] = *reinterpret_cast<const bf16x8*>(reinterpret_cast<const char*>(lds_b) + boff[ni]);
#pragma unroll
        for (int mi = 0; mi < 4; mi++)
#pragma unroll
            for (int ni = 0; ni < 4; ni++)
                acc[mi][ni] = __builtin_amdgcn_mfma_f32_16x16x32_bf16(af[mi], bfr[ni], acc[mi][ni], 0, 0, 0);
        __syncthreads();
    }

    int nb = nblk + wave_n;
    int wsel = nb >> 10;
    int h = (nb >> 6) & 15;
    int dk0 = nb & 63;
    int mglob = mblk + wave_m;
    int b = mglob >> 11;
    int s0 = mglob & (SEQ - 1);
    size_t bh = (size_t)(b * N_HEADS + h);
    const float* bias = (wsel == 0) ? bq : (wsel == 1) ? bk : bvv;
    int nn = nb & (D_MODEL - 1);
    float bval[4];
#pragma unroll
    for (int ni = 0; ni < 4; ni++) bval[ni] = bias[nn + ni * 16 + c];

    if (wsel < 2) {
        unsigned short* outp = wsel ? kb : qb;
#pragma unroll
        for (int mi = 0; mi < 4; mi++)
#pragma unroll
            for (int ni = 0; ni < 4; ni++) {
                int dk = dk0 + ni * 16 + c;
#pragma unroll
                for (int r = 0; r < 4; r++) {
                    int s = s0 + mi * 16 + g * 4 + r;
                    outp[(bh * SEQ + s) * 64 + dk] = f2bf(acc[mi][ni][r] + bval[ni]);
                }
            }
    } else {
#pragma unroll
        for (int mi = 0; mi < 4; mi++)
#pragma unroll
            for (int ni = 0; ni < 4; ni++) {
                int dk = dk0 + ni * 16 + c;
                int s = s0 + mi * 16 + g * 4;
                ushort4v o;
#pragma unroll
                for (int r = 0; r < 4; r++) o[r] = f2bf(acc[mi][ni][r] + bval[ni]);
                *reinterpret_cast<ushort4v*>(vt + (bh * 64 + dk) * SEQ + s) = o;
            }
    }
}

// ======== flash attention v2: LDS-staged K/V, fixed-shift softmax =========
// block = 4 waves = 64 queries of one head; key tile = 64
__global__ __launch_bounds__(256) void attn(const unsigned short* __restrict__ qb,
                                            const unsigned short* __restrict__ kb,
                                            const unsigned short* __restrict__ vt,
                                            const unsigned long long* __restrict__ mb,
                                            unsigned short* __restrict__ ctx) {
    __shared__ __align__(16) unsigned short lds_k[64 * 64];   // [key][dk] swizzled
    __shared__ __align__(16) unsigned short lds_v[64 * 64];   // [dk][key] swizzled
    __shared__ __align__(16) unsigned short lp[4][16][72];    // per-wave P, padded
    int tid = threadIdx.x;
    int wave = tid >> 6, lane = tid & 63;
    int c = lane & 15, g = lane >> 4;
    int bh = blockIdx.x >> 5;
    int q0 = (blockIdx.x & 31) * 64 + wave * 16;
    int b = bh >> 4;
    const unsigned short* qbase = qb + (size_t)bh * SEQ * 64;
    const unsigned short* kbase = kb + (size_t)bh * SEQ * 64;
    const unsigned short* vbase = vt + (size_t)bh * 64 * SEQ;
    const unsigned long long* mrow = mb + ((size_t)b * SEQ + q0 + g * 4) * 32;

    bf16x8 qf[2];
    qf[0] = *reinterpret_cast<const bf16x8*>(qbase + (size_t)(q0 + c) * 64 + g * 8);
    qf[1] = *reinterpret_cast<const bf16x8*>(qbase + (size_t)(q0 + c) * 64 + 32 + g * 8);

    // staging: slot j covers 8 ushorts; row = j>>3 (64 rows), octet swizzle o^(row&7)
    int j0 = wave * 128 + lane, j1 = j0 + 64;
    int sr0 = j0 >> 3, so0 = (j0 & 7) ^ (sr0 & 7);
    int sr1 = j1 >> 3, so1 = (j1 & 7) ^ (sr1 & 7);
    const unsigned short* ks0 = kbase + (size_t)sr0 * 64 + so0 * 8;
    const unsigned short* ks1 = kbase + (size_t)sr1 * 64 + so1 * 8;
    const unsigned short* vs0 = vbase + (size_t)sr0 * SEQ + so0 * 8;
    const unsigned short* vs1 = vbase + (size_t)sr1 * SEQ + so1 * 8;
    unsigned short* lk0 = lds_k + wave * 1024;
    unsigned short* lk1 = lk0 + 512;
    unsigned short* lv0 = lds_v + wave * 1024;
    unsigned short* lv1 = lv0 + 512;

    // fragment byte offsets (constant over key loop)
    int koff[4][2], voff[4][2];
#pragma unroll
    for (int st = 0; st < 4; st++) {
        int row = st * 16 + c;
#pragma unroll
        for (int kk = 0; kk < 2; kk++)
            koff[st][kk] = (row * 8 + ((kk * 4 + g) ^ (row & 7))) * 16;
    }
#pragma unroll
    for (int t = 0; t < 4; t++) {
        int row = t * 16 + c;
#pragma unroll
        for (int kk = 0; kk < 2; kk++)
            voff[t][kk] = (row * 8 + ((kk * 4 + g) ^ (row & 7))) * 16;
    }

    float lsum[4] = {0.f, 0.f, 0.f, 0.f};
    f32x4 po[4];
#pragma unroll
    for (int t = 0; t < 4; t++) po[t] = f32x4{0.f, 0.f, 0.f, 0.f};

    for (int key0 = 0; key0 < SEQ; key0 += 64) {
        load_lds16(ks0 + (size_t)key0 * 64, lk0);
        load_lds16(ks1 + (size_t)key0 * 64, lk1);
        load_lds16(vs0 + key0, lv0);
        load_lds16(vs1 + key0, lv1);
        unsigned long long wm[4];
#pragma unroll
        for (int r = 0; r < 4; r++) wm[r] = mrow[r * 32 + (key0 >> 6)];
        __syncthreads();

        f32x4 s[4];
#pragma unroll
        for (int st = 0; st < 4; st++) {
            s[st] = f32x4{0.f, 0.f, 0.f, 0.f};
            s[st] = __builtin_amdgcn_mfma_f32_16x16x32_bf16(
                qf[0], *reinterpret_cast<const bf16x8*>(reinterpret_cast<const char*>(lds_k) + koff[st][0]), s[st], 0, 0, 0);
            s[st] = __builtin_amdgcn_mfma_f32_16x16x32_bf16(
                qf[1], *reinterpret_cast<const bf16x8*>(reinterpret_cast<const char*>(lds_k) + koff[st][1]), s[st], 0, 0, 0);
        }
#pragma unroll
        for (int r = 0; r < 4; r++) {
            unsigned int lo = (unsigned int)wm[r];
            unsigned int hi = (unsigned int)(wm[r] >> 32);
#pragma unroll
            for (int st = 0; st < 4; st++) {
                unsigned int w32 = (st < 2) ? lo : hi;
                unsigned int bit = (w32 >> ((st & 1) * 16 + c)) & 1u;
                float p = bit ? 0.f : __expf(s[st][r] * 0.125f);
                lsum[r] += p;
                lp[wave][g * 4 + r][st * 16 + c] = f2bf(p);
            }
        }
        bf16x8 pf0 = *reinterpret_cast<const bf16x8*>(&lp[wave][c][g * 8]);
        bf16x8 pf1 = *reinterpret_cast<const bf16x8*>(&lp[wave][c][32 + g * 8]);
#pragma unroll
        for (int t = 0; t < 4; t++) {
            po[t] = __builtin_amdgcn_mfma_f32_16x16x32_bf16(
                pf0, *reinterpret_cast<const bf16x8*>(reinterpret_cast<const char*>(lds_v) + voff[t][0]), po[t], 0, 0, 0);
            po[t] = __builtin_amdgcn_mfma_f32_16x16x32_bf16(
                pf1, *reinterpret_cast<const bf16x8*>(reinterpret_cast<const char*>(lds_v) + voff[t][1]), po[t], 0, 0, 0);
        }
        __syncthreads();
    }

    float inv[4];
#pragma unroll
    for (int r = 0; r < 4; r++) {
        float l = lsum[r];
        l += __shfl_xor(l, 1);
        l += __shfl_xor(l, 2);
        l += __shfl_xor(l, 4);
        l += __shfl_xor(l, 8);
        inv[r] = 1.f / l;
    }
    int h = bh & 15;
#pragma unroll
    for (int t = 0; t < 4; t++)
#pragma unroll
        for (int r = 0; r < 4; r++) {
            int row = g * 4 + r;
            ctx[((size_t)b * SEQ + q0 + row) * D_MODEL + h * 64 + t * 16 + c] = f2bf(po[t][r] * inv[r]);
        }
}

// ============ output projection: m97 structure, M=8192 N=1024 K=1024 ======
__global__ __launch_bounds__(256) void oproj(const unsigned short* __restrict__ ctx,
                                             const unsigned short* __restrict__ wt,
                                             const float* __restrict__ bo,
                                             float* __restrict__ out) {
    __shared__ __align__(16) unsigned short lds_a[128 * 32];
    __shared__ __align__(16) unsigned short lds_b[128 * 32];
    int tid = threadIdx.x;
    int wave = tid >> 6, lane = tid & 63;
    int c = lane & 15, g = lane >> 4;
    int wave_m = (wave & 1) * 64, wave_n = (wave >> 1) * 64;
    int nblk = blockIdx.x * 128, mblk = blockIdx.y * 128;
    const unsigned short* wo = wt + (size_t)3 * D_MODEL * D_MODEL;

    int oct0 = wave * 128 + lane, oct1 = oct0 + 64;
    int ra0 = oct0 >> 2, ga0 = ((oct0 & 3) ^ (ra0 & 3)) * 8;
    int ra1 = oct1 >> 2, ga1 = ((oct1 & 3) ^ (ra1 & 3)) * 8;
    const unsigned short* pa0 = ctx + (size_t)(mblk + ra0) * D_MODEL + ga0;
    const unsigned short* pa1 = ctx + (size_t)(mblk + ra1) * D_MODEL + ga1;
    const unsigned short* pb0 = wo + (size_t)(nblk + ra0) * D_MODEL + ga0;
    const unsigned short* pb1 = wo + (size_t)(nblk + ra1) * D_MODEL + ga1;
    unsigned short* la0 = lds_a + wave * 1024;
    unsigned short* la1 = la0 + 512;
    unsigned short* lb0 = lds_b + wave * 1024;
    unsigned short* lb1 = lb0 + 512;

    int aoff[4], boff[4];
#pragma unroll
    for (int mi = 0; mi < 4; mi++) {
        int row = wave_m + mi * 16 + c;
        aoff[mi] = (row * 4 + (g ^ (row & 3))) * 16;
    }
#pragma unroll
    for (int ni = 0; ni < 4; ni++) {
        int row = wave_n + ni * 16 + c;
        boff[ni] = (row * 4 + (g ^ (row & 3))) * 16;
    }

    f32x4 acc[4][4];
#pragma unroll
    for (int mi = 0; mi < 4; mi++)
#pragma unroll
        for (int ni = 0; ni < 4; ni++) acc[mi][ni] = f32x4{0.f, 0.f, 0.f, 0.f};

    for (int k0 = 0; k0 < D_MODEL; k0 += 32) {
        load_lds16(pa0 + k0, la0);
        load_lds16(pa1 + k0, la1);
        load_lds16(pb0 + k0, lb0);
        load_lds16(pb1 + k0, lb1);
        __syncthreads();
        bf16x8 af[4], bfr[4];
#pragma unroll
        for (int mi = 0; mi < 4; mi++)
            af[mi] = *reinterpret_cast<const bf16x8*>(reinterpret_cast<const char*>(lds_a) + aoff[mi]);
#pragma unroll
        for (int ni = 0; ni < 4; ni++)
            bfr[ni] = *reinterpret_cast<const bf16x8*>(reinterpret_cast<const char*>(lds_b) + boff[ni]);
#pragma unroll
        for (int mi = 0; mi < 4; mi++)
#pragma unroll
            for (int ni = 0; ni < 4; ni++)
                acc[mi][ni] = __builtin_amdgcn_mfma_f32_16x16x32_bf16(af[mi], bfr[ni], acc[mi][ni], 0, 0, 0);
        __syncthreads();
    }

    float bval[4];
#pragma unroll
    for (int ni = 0; ni < 4; ni++) bval[ni] = bo[nblk + wave_n + ni * 16 + c];
#pragma unroll
    for (int mi = 0; mi < 4; mi++)
#pragma unroll
        for (int ni = 0; ni < 4; ni++) {
            int n = nblk + wave_n + ni * 16 + c;
#pragma unroll
            for (int r = 0; r < 4; r++) {
                int m = mblk + wave_m + mi * 16 + g * 4 + r;
                out[(size_t)m * D_MODEL + n] = acc[mi][ni][r] + bval[ni];
            }
        }
}

extern "C" void kernel_launch(void* const* d_in, const int* in_sizes, int n_in,
                              void* d_out, int out_size, void* d_ws, size_t ws_size,
                              hipStream_t stream) {
    const float* x    = (const float*)d_in[0];
    const int*   mask = (const int*)d_in[1];
    const float* Wq = (const float*)d_in[2];
    const float* bq = (const float*)d_in[3];
    const float* Wk = (const float*)d_in[4];
    const float* bk = (const float*)d_in[5];
    const float* Wv = (const float*)d_in[6];
    const float* bv = (const float*)d_in[7];
    const float* Wo = (const float*)d_in[8];
    const float* bo = (const float*)d_in[9];
    float* out = (float*)d_out;

    char* ws = (char*)d_ws;
    const size_t MB = 1024 * 1024;
    unsigned short* wt  = (unsigned short*)(ws + 0 * MB);    // 4x 1024x1024 bf16 = 8 MB
    unsigned short* xb  = (unsigned short*)(ws + 8 * MB);    // 8192x1024 bf16   = 16 MB
    unsigned short* qb  = (unsigned short*)(ws + 24 * MB);   // [B,H,S,dk] bf16  = 16 MB
    unsigned short* kb  = (unsigned short*)(ws + 40 * MB);   // [B,H,S,dk] bf16  = 16 MB
    unsigned short* vt  = (unsigned short*)(ws + 56 * MB);   // [B,H,dk,S] bf16  = 16 MB
    unsigned short* ctx = (unsigned short*)(ws + 72 * MB);   // [B,S,D] bf16     = 16 MB
    unsigned long long* mb = (unsigned long long*)(ws + 88 * MB); // 8192x32 u64 = 2 MB

    wprep<<<dim3(16, 16, 4), 256, 0, stream>>>(Wq, Wk, Wv, Wo, wt);
    xprep<<<dim3(MROWS * D_MODEL / 4 / 256), 256, 0, stream>>>((const float4*)x, xb);
    mprep<<<dim3(MROWS), 256, 0, stream>>>(mask, mb);
    qkv_gemm<<<dim3(24, 64), 256, 0, stream>>>(xb, wt, bq, bk, bv, qb, kb, vt);
    attn<<<dim3(2048), 256, 0, stream>>>(qb, kb, vt, mb, ctx);
    oproj<<<dim3(8, 64), 256, 0, stream>>>(ctx, wt, bo, out);
}